// Round 13
// baseline (1545.062 us; speedup 1.0000x reference)
//
#include <hip/hip_runtime.h>

#define NV   50000
#define NR   5
#define NT   8
#define CIN  64
#define COUT 64
#define BARY (NR*NT*3)      // 120
#define BK_ELEMS (NR*CIN*NT*COUT)   // 163840 fp16 (320 KB) — L2-resident
#define BM2  64
#define NBLK2 ((NV + BM2 - 1) / BM2)   // 782
#define NCH  80             // chunks: (j 0..7) x (icc 0..9), K=32 each
#define CPS  5              // chunks per super-phase
#define NPH  (NCH/CPS)      // 16 phases -> 16 barriers total

#define WL_BYTES 262144
#define SIG16_BYTES (NV*CIN*2)                            // 6.4 MB
#define WS_NEED8 (WL_BYTES + 2u*BK_ELEMS + SIG16_BYTES)   // ~7.0 MB

typedef _Float16 f16x8 __attribute__((ext_vector_type(8)));
typedef _Float16 f16x4 __attribute__((ext_vector_type(4)));
typedef float    f32x4 __attribute__((ext_vector_type(4)));

// ---------- K0a: kernel -> fp16, MFMA-FRAGMENT order ----------
// bkf[((icc*8 + m)*64 + lane)*32 + nf*8 + h] = B[col=m*64+nf*16+(lane&15)][ck=(lane>>4)*8+h]
__global__ __launch_bounds__(256) void build_bk8(
    const float* __restrict__ kern, _Float16* __restrict__ bkf)
{
    int e    = blockIdx.x * 256 + threadIdx.x;
    int h    = e & 7;
    int nf   = (e >> 3) & 3;
    int lane = (e >> 5) & 63;
    int m    = (e >> 11) & 7;
    int icc  = e >> 14;
    int d    = nf * 16 + (lane & 15);
    int ck   = (lane >> 4) * 8 + h;
    int c    = (icc & 1) * 32 + ck;
    int i    = icc >> 1;
    bkf[e] = (_Float16)kern[((i * NT + m) * CIN + c) * COUT + d];
}

// ---------- K0b: signal -> fp16 ----------
__global__ __launch_bounds__(256) void build_sig16(
    const float* __restrict__ signal, _Float16* __restrict__ sig16)
{
    int e = blockIdx.x * 256 + threadIdx.x;
    sig16[e] = (_Float16)signal[e];
}

// ---------- main v9: 5-chunk A super-tiles, 1 barrier/phase (16 total) ----------
__global__ __launch_bounds__(512, 4) void geo_mfma9(
    const float* __restrict__ bary_w,
    const int*   __restrict__ bary_idx,
    const _Float16* __restrict__ sig16,
    const _Float16* __restrict__ bkf,
    float* __restrict__ out,
    int*   __restrict__ wl)
{
    // 2 bufs x 5 slots x 4KB, each slot XOR-swizzled as in v8 (conflict-free)
    __shared__ __align__(16) _Float16 AxsF[2][CPS * 2048];
    __shared__ float nrm[BM2][NT];
    __shared__ int   besti[BM2];

    const int tid  = threadIdx.x;
    const int lane = tid & 63;
    const int wn   = tid >> 6;         // wave wn owns rotation k=wn
    const int g    = lane >> 4;
    const int l15  = lane & 15;
    const int vbase = blockIdx.x * BM2;

    const int vt = tid >> 3;
    const int cq = tid & 7;
    const int v_mine = vbase + vt;
    const bool v_ok = (v_mine < NV);

    f32x4 acc[4][4];
    {
        f32x4 z = {0.f, 0.f, 0.f, 0.f};
        #pragma unroll
        for (int mf = 0; mf < 4; ++mf)
            #pragma unroll
            for (int nf = 0; nf < 4; ++nf) acc[mf][nf] = z;
    }

    struct Gen { float w0, w1, w2; int i0, i1, i2; };
    auto LOADGEN = [&](int it2) -> Gen {
        Gen gg;
        const int itc = (it2 < NCH) ? it2 : (NCH - 1);
        const int j2   = itc / 10;
        const int icc2 = itc - j2 * 10;
        const int i2   = icc2 >> 1;
        if (v_ok) {
            const int base = v_mine * BARY + (i2 * NT + j2) * 3;
            gg.w0 = bary_w[base + 0];
            gg.w1 = bary_w[base + 1];
            gg.w2 = bary_w[base + 2];
            gg.i0 = bary_idx[base + 0];
            gg.i1 = bary_idx[base + 1];
            gg.i2 = bary_idx[base + 2];
        } else {
            gg.w0 = gg.w1 = gg.w2 = 0.f;
            gg.i0 = gg.i1 = gg.i2 = 0;
        }
        return gg;
    };

    f16x4 sA0, sA1, sA2;
    auto SIGLOAD = [&](const Gen& gg, int it2, f16x4& o0, f16x4& o1, f16x4& o2) {
        const int itc = (it2 < NCH) ? it2 : (NCH - 1);
        const int icc2 = itc - (itc / 10) * 10;
        const int coff = (icc2 & 1) * 32 + cq * 4;
        o0 = *(const f16x4*)(sig16 + gg.i0 * CIN + coff);
        o1 = *(const f16x4*)(sig16 + gg.i1 * CIN + coff);
        o2 = *(const f16x4*)(sig16 + gg.i2 * CIN + coff);
    };

    auto BFRAG = [&](int it2, f16x8& b0, f16x8& b1, f16x8& b2, f16x8& b3) {
        const int j2   = it2 / 10;
        const int icc2 = it2 - j2 * 10;
        const int m2   = (j2 + wn) & 7;
        const _Float16* src = bkf + ((icc2 * 8 + m2) * 64 + lane) * 32;
        b0 = *(const f16x8*)(src + 0);
        b1 = *(const f16x8*)(src + 8);
        b2 = *(const f16x8*)(src + 16);
        b3 = *(const f16x8*)(src + 24);
    };

    const int gw   = cq >> 1;
    const int widx = (gw * 512 + vt * 8 + (cq & 1) * 4) ^ (gw << 4);  // within-slot

    // ---- prologue: stage chunks 0..4 into buf0 (serial, one-time) ----
    for (int c = 0; c < CPS; ++c) {
        Gen gg = LOADGEN(c);
        f16x4 t0, t1, t2;
        SIGLOAD(gg, c, t0, t1, t2);
        f16x4 hv;
        #pragma unroll
        for (int e = 0; e < 4; ++e) {
            float xf = gg.w0 * (float)t0[e] + gg.w1 * (float)t1[e] + gg.w2 * (float)t2[e];
            hv[e] = (_Float16)xf;
        }
        *(f16x4*)&AxsF[0][c * 2048 + widx] = hv;
    }
    // staging pipeline for chunk 5 onward
    Gen g0 = LOADGEN(CPS);
    Gen g1 = LOADGEN(CPS + 1);
    SIGLOAD(g0, CPS, sA0, sA1, sA2);

    f16x8 bc0, bc1, bc2, bc3, bn0, bn1, bn2, bn3;
    BFRAG(0, bc0, bc1, bc2, bc3);

    asm volatile("s_waitcnt lgkmcnt(0)" ::: "memory");
    __builtin_amdgcn_s_barrier();
    asm volatile("" ::: "memory");

    for (int hs = 0; hs < NPH; ++hs) {
        const int rbuf = hs & 1;
        #pragma unroll
        for (int c = 0; c < CPS; ++c) {
            const int it = hs * CPS + c;
            const int st = it + CPS;      // chunk being staged (next phase, slot c)

            // B fragments for next chunk (in flight under this chunk's MFMAs;
            // crosses the phase barrier for c==CPS-1 — raw barrier keeps vmcnt)
            if (it + 1 < NCH) BFRAG(it + 1, bn0, bn1, bn2, bn3);

            // A fragments for this chunk
            f16x8 af[4];
            #pragma unroll
            for (int mf = 0; mf < 4; ++mf) {
                const int row = mf * 16 + l15;
                af[mf] = *(const f16x8*)&AxsF[rbuf][c * 2048 + ((g * 512 + row * 8) ^ (g << 4))];
            }

            // stage chunk st into the OTHER buffer, slot c (no barrier needed)
            if (st < NCH) {
                f16x4 hv;
                #pragma unroll
                for (int e = 0; e < 4; ++e) {
                    float xf = g0.w0 * (float)sA0[e]
                             + g0.w1 * (float)sA1[e]
                             + g0.w2 * (float)sA2[e];
                    hv[e] = (_Float16)xf;
                }
                *(f16x4*)&AxsF[rbuf ^ 1][c * 2048 + widx] = hv;
                SIGLOAD(g1, st + 1, sA0, sA1, sA2);
                g0 = g1;
                g1 = LOADGEN(st + 2);
            }

            // 16 MFMAs
            #pragma unroll
            for (int mf = 0; mf < 4; ++mf) {
                acc[mf][0] = __builtin_amdgcn_mfma_f32_16x16x32_f16(af[mf], bc0, acc[mf][0], 0, 0, 0);
                acc[mf][1] = __builtin_amdgcn_mfma_f32_16x16x32_f16(af[mf], bc1, acc[mf][1], 0, 0, 0);
                acc[mf][2] = __builtin_amdgcn_mfma_f32_16x16x32_f16(af[mf], bc2, acc[mf][2], 0, 0, 0);
                acc[mf][3] = __builtin_amdgcn_mfma_f32_16x16x32_f16(af[mf], bc3, acc[mf][3], 0, 0, 0);
            }
            bc0 = bn0; bc1 = bn1; bc2 = bn2; bc3 = bn3;
        }

        // ONE barrier per phase: drains ds (A writes visible + A reads done);
        // global loads (B, sig, bary) stay in flight across it.
        asm volatile("s_waitcnt lgkmcnt(0)" ::: "memory");
        __builtin_amdgcn_s_barrier();
        asm volatile("" ::: "memory");
    }

    // ---- epilogue: wave wn owns rotation wn; norms per row ----
    #pragma unroll
    for (int mf = 0; mf < 4; ++mf)
        #pragma unroll
        for (int ri = 0; ri < 4; ++ri) {
            float s = 0.f;
            #pragma unroll
            for (int nf = 0; nf < 4; ++nf) {
                float vv = acc[mf][nf][ri];
                s = fmaf(vv, vv, s);
            }
            #pragma unroll
            for (int off = 1; off < 16; off <<= 1)
                s += __shfl_xor(s, off);
            if (l15 == 0) nrm[mf * 16 + g * 4 + ri][wn] = s;
        }
    __syncthreads();

    if (tid < BM2) {
        const int v = vbase + tid;
        float bn = nrm[tid][0];
        float sec = -1e30f;
        int best = 0;
        #pragma unroll
        for (int k = 1; k < NT; ++k) {
            float nv = nrm[tid][k];
            if (nv > bn)       { sec = bn; bn = nv; best = k; }
            else if (nv > sec) { sec = nv; }
        }
        // fp16-input norm^2 error ~1.2e-2 sigma; ~6 sigma + rel term
        const bool flag = (bn - sec) <= (7e-2f + 2e-3f * bn);
        besti[tid] = flag ? -1 : best;
        if (flag && v < NV) { int p = atomicAdd(wl, 1); wl[1 + p] = v; }
    }
    __syncthreads();

    #pragma unroll
    for (int mf = 0; mf < 4; ++mf)
        #pragma unroll
        for (int ri = 0; ri < 4; ++ri) {
            const int row = mf * 16 + g * 4 + ri;
            const int v   = vbase + row;
            const int bsel = (v < NV) ? besti[row] : -1;
            if (bsel == wn) {
                #pragma unroll
                for (int nf = 0; nf < 4; ++nf) {
                    const int d = nf * 16 + l15;
                    out[v * COUT + d] = fmaxf(acc[mf][nf][ri], 0.0f);
                }
            }
        }
}

// ---------- parallel fp64 refine: one BLOCK (4 waves) per vertex ----------
__global__ __launch_bounds__(256) void geo_refine_f64p(
    const float* __restrict__ signal,
    const float* __restrict__ bary_w,
    const int*   __restrict__ bary_idx,
    const float* __restrict__ kern,
    float*       __restrict__ out,
    const int*   __restrict__ wl,
    int nall)
{
    __shared__ __align__(16) float xs[NR][CIN][NT];
    __shared__ double part[4][NT][COUT];
    __shared__ double convl[NT][COUT];
    __shared__ double nks[NT];
    __shared__ int bestS;

    const int tid  = threadIdx.x;
    const int wave = tid >> 6;
    const int lane = tid & 63;
    const int count = wl ? wl[0] : nall;

    for (int w = blockIdx.x; w < count; w += gridDim.x) {
        const int v = wl ? wl[1 + w] : w;

        for (int ij = wave; ij < NR * NT; ij += 4) {
            const int i = ij >> 3, j = ij & 7;
            const int base = v * BARY + ij * 3;
            const float w0 = bary_w[base], w1 = bary_w[base+1], w2 = bary_w[base+2];
            const int   i0 = bary_idx[base], i1 = bary_idx[base+1], i2 = bary_idx[base+2];
            xs[i][lane][j] = w0 * signal[i0*CIN + lane]
                           + w1 * signal[i1*CIN + lane]
                           + w2 * signal[i2*CIN + lane];
        }
        __syncthreads();

        double acc[NT];
        #pragma unroll
        for (int k = 0; k < NT; ++k) acc[k] = 0.0;

        for (int r = wave * 80; r < wave * 80 + 80; ++r) {
            const int i = r >> 6, c = r & 63;
            const float4 xa = *reinterpret_cast<const float4*>(&xs[i][c][0]);
            const float4 xb = *reinterpret_cast<const float4*>(&xs[i][c][4]);
            const double x8[NT] = {(double)xa.x, (double)xa.y, (double)xa.z, (double)xa.w,
                                   (double)xb.x, (double)xb.y, (double)xb.z, (double)xb.w};
            #pragma unroll
            for (int mm = 0; mm < NT; ++mm) {
                const double kv = (double)kern[((i * NT + mm) * CIN + c) * COUT + lane];
                #pragma unroll
                for (int k = 0; k < NT; ++k)
                    acc[k] = fma(x8[(mm - k + NT) & (NT - 1)], kv, acc[k]);
            }
        }
        #pragma unroll
        for (int k = 0; k < NT; ++k) part[wave][k][lane] = acc[k];
        __syncthreads();

        for (int kd = tid; kd < NT * COUT; kd += 256) {
            const int k = kd >> 6, d = kd & 63;
            convl[k][d] = ((part[0][k][d] + part[1][k][d])
                         + (part[2][k][d] + part[3][k][d]));
        }
        __syncthreads();

        for (int k = wave; k < NT; k += 4) {
            double n = convl[k][lane] * convl[k][lane];
            #pragma unroll
            for (int off = 32; off >= 1; off >>= 1) n += __shfl_xor(n, off);
            if (lane == 0) nks[k] = n;
        }
        __syncthreads();

        if (tid == 0) {
            int best = 0; double bn = nks[0];
            #pragma unroll
            for (int k = 1; k < NT; ++k)
                if (nks[k] > bn) { bn = nks[k]; best = k; }
            bestS = best;
        }
        __syncthreads();

        if (tid < COUT) out[v * COUT + tid] = fmaxf((float)convl[bestS][tid], 0.0f);
        __syncthreads();
    }
}

extern "C" void kernel_launch(void* const* d_in, const int* in_sizes, int n_in,
                              void* d_out, int out_size, void* d_ws, size_t ws_size,
                              hipStream_t stream) {
    const float* signal   = (const float*)d_in[0];
    const float* bary_w   = (const float*)d_in[1];
    const int*   bary_idx = (const int*)d_in[2];
    const float* kern     = (const float*)d_in[3];
    float* out = (float*)d_out;

    if (ws_size >= (size_t)WS_NEED8) {
        int* wl = (int*)d_ws;
        _Float16* bkf   = (_Float16*)((char*)d_ws + WL_BYTES);
        _Float16* sig16 = (_Float16*)((char*)d_ws + WL_BYTES + 2u * BK_ELEMS);
        hipMemsetAsync(wl, 0, sizeof(int), stream);
        build_bk8<<<dim3(BK_ELEMS / 256), dim3(256), 0, stream>>>(kern, bkf);
        build_sig16<<<dim3(NV * CIN / 256), dim3(256), 0, stream>>>(signal, sig16);
        geo_mfma9<<<dim3(NBLK2), dim3(512), 0, stream>>>(
            bary_w, bary_idx, sig16, bkf, out, wl);
        geo_refine_f64p<<<dim3(1024), dim3(256), 0, stream>>>(
            signal, bary_w, bary_idx, kern, out, wl, 0);
    } else {
        geo_refine_f64p<<<dim3(1024), dim3(256), 0, stream>>>(
            signal, bary_w, bary_idx, kern, out, nullptr, NV);
    }
}

// Round 14
// 1297.704 us; speedup vs baseline: 1.1906x; 1.1906x over previous
//
#include <hip/hip_runtime.h>

#define NV   50000
#define NR   5
#define NT   8
#define CIN  64
#define COUT 64
#define BARY (NR*NT*3)      // 120
#define BK_ELEMS (NR*CIN*NT*COUT)   // 163840 fp16 (320 KB) — L2-resident
#define BM2  64
#define NBLK2 ((NV + BM2 - 1) / BM2)   // 782
#define NCH  80             // chunks: (j 0..7) x (icc 0..9), K=32 each
#define CPS  8              // chunks per super-phase
#define NPH  (NCH/CPS)      // 10 phases -> 10 barriers total

#define WL_BYTES 262144
#define SIG16_BYTES (NV*CIN*2)                            // 6.4 MB
#define WS_NEED8 (WL_BYTES + 2u*BK_ELEMS + SIG16_BYTES)   // ~7.0 MB

typedef _Float16 f16x8 __attribute__((ext_vector_type(8)));
typedef _Float16 f16x4 __attribute__((ext_vector_type(4)));
typedef float    f32x4 __attribute__((ext_vector_type(4)));

// ---------- K0a: kernel -> fp16, MFMA-FRAGMENT order ----------
// bkf[((icc*8 + m)*64 + lane)*32 + nf*8 + h] = B[col=m*64+nf*16+(lane&15)][ck=(lane>>4)*8+h]
__global__ __launch_bounds__(256) void build_bk8(
    const float* __restrict__ kern, _Float16* __restrict__ bkf)
{
    int e    = blockIdx.x * 256 + threadIdx.x;
    int h    = e & 7;
    int nf   = (e >> 3) & 3;
    int lane = (e >> 5) & 63;
    int m    = (e >> 11) & 7;
    int icc  = e >> 14;
    int d    = nf * 16 + (lane & 15);
    int ck   = (lane >> 4) * 8 + h;
    int c    = (icc & 1) * 32 + ck;
    int i    = icc >> 1;
    bkf[e] = (_Float16)kern[((i * NT + m) * CIN + c) * COUT + d];
}

// ---------- K0b: signal -> fp16 ----------
__global__ __launch_bounds__(256) void build_sig16(
    const float* __restrict__ signal, _Float16* __restrict__ sig16)
{
    int e = blockIdx.x * 256 + threadIdx.x;
    sig16[e] = (_Float16)signal[e];
}

// ---------- main v10: 8-chunk super-tiles, unroll-1 (NO hoisting), 10 barriers ----------
__global__ __launch_bounds__(512, 4) void geo_mfma10(
    const float* __restrict__ bary_w,
    const int*   __restrict__ bary_idx,
    const _Float16* __restrict__ sig16,
    const _Float16* __restrict__ bkf,
    float* __restrict__ out,
    int*   __restrict__ wl)
{
    // 2 bufs x 8 slots x 4KB, each slot XOR-swizzled as in v8 (conflict-free)
    __shared__ __align__(16) _Float16 AxsF[2][CPS * 2048];  // 64 KB
    __shared__ float nrm[BM2][NT];
    __shared__ int   besti[BM2];

    const int tid  = threadIdx.x;
    const int lane = tid & 63;
    const int wn   = tid >> 6;         // wave wn owns rotation k=wn
    const int g    = lane >> 4;
    const int l15  = lane & 15;
    const int vbase = blockIdx.x * BM2;

    const int vt = tid >> 3;
    const int cq = tid & 7;
    const int v_mine = vbase + vt;
    const bool v_ok = (v_mine < NV);

    f32x4 acc[4][4];
    {
        f32x4 z = {0.f, 0.f, 0.f, 0.f};
        #pragma unroll
        for (int mf = 0; mf < 4; ++mf)
            #pragma unroll
            for (int nf = 0; nf < 4; ++nf) acc[mf][nf] = z;
    }

    struct Gen { float w0, w1, w2; int i0, i1, i2; };
    auto LOADGEN = [&](int it2) -> Gen {
        Gen gg;
        const int itc = (it2 < NCH) ? it2 : (NCH - 1);
        const int j2   = itc / 10;
        const int icc2 = itc - j2 * 10;
        const int i2   = icc2 >> 1;
        if (v_ok) {
            const int base = v_mine * BARY + (i2 * NT + j2) * 3;
            gg.w0 = bary_w[base + 0];
            gg.w1 = bary_w[base + 1];
            gg.w2 = bary_w[base + 2];
            gg.i0 = bary_idx[base + 0];
            gg.i1 = bary_idx[base + 1];
            gg.i2 = bary_idx[base + 2];
        } else {
            gg.w0 = gg.w1 = gg.w2 = 0.f;
            gg.i0 = gg.i1 = gg.i2 = 0;
        }
        return gg;
    };

    f16x4 sA0, sA1, sA2;
    auto SIGLOAD = [&](const Gen& gg, int it2, f16x4& o0, f16x4& o1, f16x4& o2) {
        const int itc = (it2 < NCH) ? it2 : (NCH - 1);
        const int icc2 = itc - (itc / 10) * 10;
        const int coff = (icc2 & 1) * 32 + cq * 4;
        o0 = *(const f16x4*)(sig16 + gg.i0 * CIN + coff);
        o1 = *(const f16x4*)(sig16 + gg.i1 * CIN + coff);
        o2 = *(const f16x4*)(sig16 + gg.i2 * CIN + coff);
    };

    auto BFRAG = [&](int it2, f16x8& b0, f16x8& b1, f16x8& b2, f16x8& b3) {
        const int j2   = it2 / 10;
        const int icc2 = it2 - j2 * 10;
        const int m2   = (j2 + wn) & 7;
        const _Float16* src = bkf + ((icc2 * 8 + m2) * 64 + lane) * 32;
        b0 = *(const f16x8*)(src + 0);
        b1 = *(const f16x8*)(src + 8);
        b2 = *(const f16x8*)(src + 16);
        b3 = *(const f16x8*)(src + 24);
    };

    const int gw   = cq >> 1;
    const int widx = (gw * 512 + vt * 8 + (cq & 1) * 4) ^ (gw << 4);  // within-slot

    // ---- prologue: stage chunks 0..CPS-1 into buf0 (serial, one-time) ----
    #pragma unroll 1
    for (int c = 0; c < CPS; ++c) {
        Gen gg = LOADGEN(c);
        f16x4 t0, t1, t2;
        SIGLOAD(gg, c, t0, t1, t2);
        f16x4 hv;
        #pragma unroll
        for (int e = 0; e < 4; ++e) {
            float xf = gg.w0 * (float)t0[e] + gg.w1 * (float)t1[e] + gg.w2 * (float)t2[e];
            hv[e] = (_Float16)xf;
        }
        *(f16x4*)&AxsF[0][c * 2048 + widx] = hv;
    }
    Gen g0 = LOADGEN(CPS);
    Gen g1 = LOADGEN(CPS + 1);
    SIGLOAD(g0, CPS, sA0, sA1, sA2);

    f16x8 bc0, bc1, bc2, bc3, bn0, bn1, bn2, bn3;
    BFRAG(0, bc0, bc1, bc2, bc3);

    asm volatile("s_waitcnt lgkmcnt(0)" ::: "memory");
    __builtin_amdgcn_s_barrier();
    asm volatile("" ::: "memory");

    #pragma unroll 1
    for (int hs = 0; hs < NPH; ++hs) {
        const int rbuf = hs & 1;
        // unroll 1: v13's full unroll made the compiler hoist ALL slot B-loads
        // (80 live B-regs -> 2.7 GB spill). Backedge pins the live set to v8's.
        #pragma unroll 1
        for (int c = 0; c < CPS; ++c) {
            const int it = hs * CPS + c;
            const int st = it + CPS;      // chunk staged into the other buffer

            if (it + 1 < NCH) BFRAG(it + 1, bn0, bn1, bn2, bn3);

            f16x8 af[4];
            #pragma unroll
            for (int mf = 0; mf < 4; ++mf) {
                const int row = mf * 16 + l15;
                af[mf] = *(const f16x8*)&AxsF[rbuf][c * 2048 + ((g * 512 + row * 8) ^ (g << 4))];
            }

            if (st < NCH) {
                f16x4 hv;
                #pragma unroll
                for (int e = 0; e < 4; ++e) {
                    float xf = g0.w0 * (float)sA0[e]
                             + g0.w1 * (float)sA1[e]
                             + g0.w2 * (float)sA2[e];
                    hv[e] = (_Float16)xf;
                }
                *(f16x4*)&AxsF[rbuf ^ 1][c * 2048 + widx] = hv;
                SIGLOAD(g1, st + 1, sA0, sA1, sA2);
                g0 = g1;
                g1 = LOADGEN(st + 2);
            }

            __builtin_amdgcn_s_setprio(1);
            #pragma unroll
            for (int mf = 0; mf < 4; ++mf) {
                acc[mf][0] = __builtin_amdgcn_mfma_f32_16x16x32_f16(af[mf], bc0, acc[mf][0], 0, 0, 0);
                acc[mf][1] = __builtin_amdgcn_mfma_f32_16x16x32_f16(af[mf], bc1, acc[mf][1], 0, 0, 0);
                acc[mf][2] = __builtin_amdgcn_mfma_f32_16x16x32_f16(af[mf], bc2, acc[mf][2], 0, 0, 0);
                acc[mf][3] = __builtin_amdgcn_mfma_f32_16x16x32_f16(af[mf], bc3, acc[mf][3], 0, 0, 0);
            }
            __builtin_amdgcn_s_setprio(0);
            bc0 = bn0; bc1 = bn1; bc2 = bn2; bc3 = bn3;
        }

        // ONE raw barrier per phase; global loads stay in flight across it.
        asm volatile("s_waitcnt lgkmcnt(0)" ::: "memory");
        __builtin_amdgcn_s_barrier();
        asm volatile("" ::: "memory");
    }

    // ---- epilogue: wave wn owns rotation wn; norms per row ----
    #pragma unroll
    for (int mf = 0; mf < 4; ++mf)
        #pragma unroll
        for (int ri = 0; ri < 4; ++ri) {
            float s = 0.f;
            #pragma unroll
            for (int nf = 0; nf < 4; ++nf) {
                float vv = acc[mf][nf][ri];
                s = fmaf(vv, vv, s);
            }
            #pragma unroll
            for (int off = 1; off < 16; off <<= 1)
                s += __shfl_xor(s, off);
            if (l15 == 0) nrm[mf * 16 + g * 4 + ri][wn] = s;
        }
    __syncthreads();

    if (tid < BM2) {
        const int v = vbase + tid;
        float bn = nrm[tid][0];
        float sec = -1e30f;
        int best = 0;
        #pragma unroll
        for (int k = 1; k < NT; ++k) {
            float nv = nrm[tid][k];
            if (nv > bn)       { sec = bn; bn = nv; best = k; }
            else if (nv > sec) { sec = nv; }
        }
        // gap-err sigma ~3.6e-3 (fp16 inputs, fp32 MFMA accum) -> ~11 sigma
        const bool flag = (bn - sec) <= (3.0e-2f + 4e-4f * bn);
        besti[tid] = flag ? -1 : best;
        if (flag && v < NV) { int p = atomicAdd(wl, 1); wl[1 + p] = v; }
    }
    __syncthreads();

    #pragma unroll
    for (int mf = 0; mf < 4; ++mf)
        #pragma unroll
        for (int ri = 0; ri < 4; ++ri) {
            const int row = mf * 16 + g * 4 + ri;
            const int v   = vbase + row;
            const int bsel = (v < NV) ? besti[row] : -1;
            if (bsel == wn) {
                #pragma unroll
                for (int nf = 0; nf < 4; ++nf) {
                    const int d = nf * 16 + l15;
                    out[v * COUT + d] = fmaxf(acc[mf][nf][ri], 0.0f);
                }
            }
        }
}

// ---------- parallel fp64 refine: one BLOCK (4 waves) per vertex ----------
__global__ __launch_bounds__(256) void geo_refine_f64p(
    const float* __restrict__ signal,
    const float* __restrict__ bary_w,
    const int*   __restrict__ bary_idx,
    const float* __restrict__ kern,
    float*       __restrict__ out,
    const int*   __restrict__ wl,
    int nall)
{
    __shared__ __align__(16) float xs[NR][CIN][NT];
    __shared__ double part[4][NT][COUT];
    __shared__ double convl[NT][COUT];
    __shared__ double nks[NT];
    __shared__ int bestS;

    const int tid  = threadIdx.x;
    const int wave = tid >> 6;
    const int lane = tid & 63;
    const int count = wl ? wl[0] : nall;

    for (int w = blockIdx.x; w < count; w += gridDim.x) {
        const int v = wl ? wl[1 + w] : w;

        for (int ij = wave; ij < NR * NT; ij += 4) {
            const int i = ij >> 3, j = ij & 7;
            const int base = v * BARY + ij * 3;
            const float w0 = bary_w[base], w1 = bary_w[base+1], w2 = bary_w[base+2];
            const int   i0 = bary_idx[base], i1 = bary_idx[base+1], i2 = bary_idx[base+2];
            xs[i][lane][j] = w0 * signal[i0*CIN + lane]
                           + w1 * signal[i1*CIN + lane]
                           + w2 * signal[i2*CIN + lane];
        }
        __syncthreads();

        double acc[NT];
        #pragma unroll
        for (int k = 0; k < NT; ++k) acc[k] = 0.0;

        for (int r = wave * 80; r < wave * 80 + 80; ++r) {
            const int i = r >> 6, c = r & 63;
            const float4 xa = *reinterpret_cast<const float4*>(&xs[i][c][0]);
            const float4 xb = *reinterpret_cast<const float4*>(&xs[i][c][4]);
            const double x8[NT] = {(double)xa.x, (double)xa.y, (double)xa.z, (double)xa.w,
                                   (double)xb.x, (double)xb.y, (double)xb.z, (double)xb.w};
            #pragma unroll
            for (int mm = 0; mm < NT; ++mm) {
                const double kv = (double)kern[((i * NT + mm) * CIN + c) * COUT + lane];
                #pragma unroll
                for (int k = 0; k < NT; ++k)
                    acc[k] = fma(x8[(mm - k + NT) & (NT - 1)], kv, acc[k]);
            }
        }
        #pragma unroll
        for (int k = 0; k < NT; ++k) part[wave][k][lane] = acc[k];
        __syncthreads();

        for (int kd = tid; kd < NT * COUT; kd += 256) {
            const int k = kd >> 6, d = kd & 63;
            convl[k][d] = ((part[0][k][d] + part[1][k][d])
                         + (part[2][k][d] + part[3][k][d]));
        }
        __syncthreads();

        for (int k = wave; k < NT; k += 4) {
            double n = convl[k][lane] * convl[k][lane];
            #pragma unroll
            for (int off = 32; off >= 1; off >>= 1) n += __shfl_xor(n, off);
            if (lane == 0) nks[k] = n;
        }
        __syncthreads();

        if (tid == 0) {
            int best = 0; double bn = nks[0];
            #pragma unroll
            for (int k = 1; k < NT; ++k)
                if (nks[k] > bn) { bn = nks[k]; best = k; }
            bestS = best;
        }
        __syncthreads();

        if (tid < COUT) out[v * COUT + tid] = fmaxf((float)convl[bestS][tid], 0.0f);
        __syncthreads();
    }
}

extern "C" void kernel_launch(void* const* d_in, const int* in_sizes, int n_in,
                              void* d_out, int out_size, void* d_ws, size_t ws_size,
                              hipStream_t stream) {
    const float* signal   = (const float*)d_in[0];
    const float* bary_w   = (const float*)d_in[1];
    const int*   bary_idx = (const int*)d_in[2];
    const float* kern     = (const float*)d_in[3];
    float* out = (float*)d_out;

    if (ws_size >= (size_t)WS_NEED8) {
        int* wl = (int*)d_ws;
        _Float16* bkf   = (_Float16*)((char*)d_ws + WL_BYTES);
        _Float16* sig16 = (_Float16*)((char*)d_ws + WL_BYTES + 2u * BK_ELEMS);
        hipMemsetAsync(wl, 0, sizeof(int), stream);
        build_bk8<<<dim3(BK_ELEMS / 256), dim3(256), 0, stream>>>(kern, bkf);
        build_sig16<<<dim3(NV * CIN / 256), dim3(256), 0, stream>>>(signal, sig16);
        geo_mfma10<<<dim3(NBLK2), dim3(512), 0, stream>>>(
            bary_w, bary_idx, sig16, bkf, out, wl);
        geo_refine_f64p<<<dim3(1024), dim3(256), 0, stream>>>(
            signal, bary_w, bary_idx, kern, out, wl, 0);
    } else {
        geo_refine_f64p<<<dim3(1024), dim3(256), 0, stream>>>(
            signal, bary_w, bary_idx, kern, out, nullptr, NV);
    }
}

// Round 15
// 1134.515 us; speedup vs baseline: 1.3619x; 1.1438x over previous
//
#include <hip/hip_runtime.h>

#define NV   50000
#define NR   5
#define NT   8
#define CIN  64
#define COUT 64
#define BARY (NR*NT*3)      // 120
#define BK_ELEMS (NR*CIN*NT*COUT)   // 163840 fp16 (320 KB) — L2-resident
#define BM2  64
#define NBLK2 ((NV + BM2 - 1) / BM2)   // 782
#define NCH  80             // chunks: (j 0..7) x (icc 0..9), K=32 each

#define WL_BYTES 262144
#define SIG16_BYTES (NV*CIN*2)                            // 6.4 MB
#define WS_NEED8 (WL_BYTES + 2u*BK_ELEMS + SIG16_BYTES)   // ~7.0 MB

typedef _Float16 f16x8 __attribute__((ext_vector_type(8)));
typedef _Float16 f16x4 __attribute__((ext_vector_type(4)));
typedef float    f32x4 __attribute__((ext_vector_type(4)));

typedef const __attribute__((address_space(1))) void GAS;
typedef __attribute__((address_space(3))) void LAS;

// ---------- K0a: kernel -> fp16, fragment order WITH sigma permutation baked ----------
// LDS staging is a LINEAR copy (global_load_lds); the read side uses
// u = f ^ ((f>>3)&7) so we store bkf_p[icc][u] = frag_value(icc, sigma(u)).
// frag unit f = (m*64 + lane)*4 + q holds B[d = q*16 + (lane&15)][ck = (lane>>4)*8 .. +8]
__global__ __launch_bounds__(256) void build_bk11(
    const float* __restrict__ kern, _Float16* __restrict__ bkf)
{
    int e    = blockIdx.x * 256 + threadIdx.x;
    int h    = e & 7;
    int u    = (e >> 3) & 2047;
    int icc  = e >> 14;
    int s    = u ^ ((u >> 3) & 7);     // involution: bits 3-5 untouched
    int q    = s & 3;
    int lane = (s >> 2) & 63;
    int m    = (s >> 8) & 7;
    int d    = q * 16 + (lane & 15);
    int ck   = (lane >> 4) * 8 + h;
    int c    = (icc & 1) * 32 + ck;
    int i    = icc >> 1;
    bkf[e] = (_Float16)kern[((i * NT + m) * CIN + c) * COUT + d];
}

// ---------- K0b: signal -> fp16 ----------
__global__ __launch_bounds__(256) void build_sig16(
    const float* __restrict__ signal, _Float16* __restrict__ sig16)
{
    int e = blockIdx.x * 256 + threadIdx.x;
    sig16[e] = (_Float16)signal[e];
}

// ---------- main v11: B via global_load_lds dbuf, counted vmcnt, unroll-4 ----------
__global__ __launch_bounds__(512, 4) void geo_mfma11(
    const float* __restrict__ bary_w,
    const int*   __restrict__ bary_idx,
    const _Float16* __restrict__ sig16,
    const _Float16* __restrict__ bkf,
    float* __restrict__ out,
    int*   __restrict__ wl)
{
    __shared__ __align__(16) _Float16 Blds[2][16384];       // 2 x 32 KB
    __shared__ __align__(16) _Float16 AxsF[4 * BM2 * 8];    // 4 KB (v8 layout)
    __shared__ float nrm[BM2][NT];
    __shared__ int   besti[BM2];

    const int tid  = threadIdx.x;
    const int lane = tid & 63;
    const int wn   = tid >> 6;         // wave wn owns rotation k=wn
    const int g    = lane >> 4;
    const int l15  = lane & 15;
    const int vbase = blockIdx.x * BM2;

    const int vt = tid >> 3;
    const int cq = tid & 7;
    const int v_mine = vbase + vt;
    const bool v_ok = (v_mine < NV);

    f32x4 acc[4][4];
    {
        f32x4 z = {0.f, 0.f, 0.f, 0.f};
        #pragma unroll
        for (int mf = 0; mf < 4; ++mf)
            #pragma unroll
            for (int nf = 0; nf < 4; ++nf) acc[mf][nf] = z;
    }

    struct Gen { float w0, w1, w2; int i0, i1, i2; };
    auto LOADGEN = [&](int it2) -> Gen {
        Gen gg;
        const int itc = (it2 < NCH) ? it2 : (NCH - 1);
        const int j2   = itc / 10;
        const int icc2 = itc - j2 * 10;
        const int i2   = icc2 >> 1;
        if (v_ok) {
            const int base = v_mine * BARY + (i2 * NT + j2) * 3;
            gg.w0 = bary_w[base + 0];
            gg.w1 = bary_w[base + 1];
            gg.w2 = bary_w[base + 2];
            gg.i0 = bary_idx[base + 0];
            gg.i1 = bary_idx[base + 1];
            gg.i2 = bary_idx[base + 2];
        } else {
            gg.w0 = gg.w1 = gg.w2 = 0.f;
            gg.i0 = gg.i1 = gg.i2 = 0;
        }
        return gg;
    };

    auto SIGLOAD = [&](const Gen& gg, int it2, f16x4& o0, f16x4& o1, f16x4& o2) {
        const int itc = (it2 < NCH) ? it2 : (NCH - 1);
        const int icc2 = itc - (itc / 10) * 10;
        const int coff = (icc2 & 1) * 32 + cq * 4;
        o0 = *(const f16x4*)(sig16 + gg.i0 * CIN + coff);
        o1 = *(const f16x4*)(sig16 + gg.i1 * CIN + coff);
        o2 = *(const f16x4*)(sig16 + gg.i2 * CIN + coff);
    };

    // B chunk -> LDS via global_load_lds (linear copy; permutation pre-baked).
    // Wave wn covers units [wn*256 + p*64 + lane), p=0..3.
    auto BSTAGE = [&](int it2, int buf) {
        const int icc2 = it2 - (it2 / 10) * 10;
        const _Float16* src0 = bkf + icc2 * 16384 + (wn * 256) * 8 + lane * 8;
        _Float16* dst0 = &Blds[buf][(wn * 256) * 8];
        #pragma unroll
        for (int p = 0; p < 4; ++p) {
            __builtin_amdgcn_global_load_lds(
                (GAS*)(src0 + p * 512),          // per-lane global src
                (LAS*)(dst0 + p * 512),          // wave-uniform LDS base (+lane*16 by HW)
                16, 0, 0);
        }
    };

    const int gw   = cq >> 1;
    const int widx = (gw * 512 + vt * 8 + (cq & 1) * 4) ^ (gw << 4);

    // ---- one ITER body; all gen/sig registers statically named (rule #20) ----
    auto ITER = [&](int it, const Gen& g_use, const Gen& g_next, Gen& g_load,
                    const f16x4* sU, f16x4* sL) {
        const int cur = it & 1;
        // phase1: B-stage first (oldest in vm queue), then bary, x, sig
        if (it + 1 < NCH) BSTAGE(it + 1, cur ^ 1);
        __builtin_amdgcn_sched_barrier(0);
        g_load = LOADGEN(it + 2);
        {
            f16x4 hv;
            #pragma unroll
            for (int e = 0; e < 4; ++e) {
                float xf = g_use.w0 * (float)sU[0][e]
                         + g_use.w1 * (float)sU[1][e]
                         + g_use.w2 * (float)sU[2][e];
                hv[e] = (_Float16)xf;
            }
            *(f16x4*)&AxsF[widx] = hv;
        }
        SIGLOAD(g_next, it + 1, sL[0], sL[1], sL[2]);
        __builtin_amdgcn_sched_barrier(0);
        // B(it) has >=14 younger vm ops here (4+k+3 per iter, k>=2) -> vmcnt(14)
        asm volatile("s_waitcnt vmcnt(14) lgkmcnt(0)" ::: "memory");
        __builtin_amdgcn_s_barrier();
        asm volatile("" ::: "memory");

        // phase2: fragments from LDS, 16 MFMA
        const int j = it / 10;
        const int m = (j + wn) & 7;
        f16x8 bf[4];
        #pragma unroll
        for (int q = 0; q < 4; ++q) {
            const int f = ((m * 64 + lane) << 2) + q;
            const int u = f ^ ((f >> 3) & 7);
            bf[q] = *(const f16x8*)&Blds[cur][u * 8];
        }
        f16x8 af[4];
        #pragma unroll
        for (int mf = 0; mf < 4; ++mf) {
            const int row = mf * 16 + l15;
            af[mf] = *(const f16x8*)&AxsF[(g * 512 + row * 8) ^ (g << 4)];
        }
        __builtin_amdgcn_s_setprio(1);
        #pragma unroll
        for (int mf = 0; mf < 4; ++mf) {
            acc[mf][0] = __builtin_amdgcn_mfma_f32_16x16x32_f16(af[mf], bf[0], acc[mf][0], 0, 0, 0);
            acc[mf][1] = __builtin_amdgcn_mfma_f32_16x16x32_f16(af[mf], bf[1], acc[mf][1], 0, 0, 0);
            acc[mf][2] = __builtin_amdgcn_mfma_f32_16x16x32_f16(af[mf], bf[2], acc[mf][2], 0, 0, 0);
            acc[mf][3] = __builtin_amdgcn_mfma_f32_16x16x32_f16(af[mf], bf[3], acc[mf][3], 0, 0, 0);
        }
        __builtin_amdgcn_s_setprio(0);
        asm volatile("" ::: "memory");
        __builtin_amdgcn_s_barrier();   // AxsF free; Blds[cur] not rewritten for 2 iters
        asm volatile("" ::: "memory");
    };

    // ---- prologue ----
    BSTAGE(0, 0);
    Gen g0 = LOADGEN(0);
    Gen g1 = LOADGEN(1);
    Gen g2, g3;
    f16x4 sE[3], sO[3];
    SIGLOAD(g0, 0, sE[0], sE[1], sE[2]);

    // ---- main loop: unroll-4 with static register rotation (no copies) ----
    #pragma unroll 1
    for (int ib = 0; ib < NCH; ib += 4) {
        ITER(ib + 0, g0, g1, g2, sE, sO);
        ITER(ib + 1, g1, g2, g3, sO, sE);
        ITER(ib + 2, g2, g3, g0, sE, sO);
        ITER(ib + 3, g3, g0, g1, sO, sE);
    }

    // ---- epilogue: wave wn owns rotation wn; norms per row ----
    #pragma unroll
    for (int mf = 0; mf < 4; ++mf)
        #pragma unroll
        for (int ri = 0; ri < 4; ++ri) {
            float s = 0.f;
            #pragma unroll
            for (int nf = 0; nf < 4; ++nf) {
                float vv = acc[mf][nf][ri];
                s = fmaf(vv, vv, s);
            }
            #pragma unroll
            for (int off = 1; off < 16; off <<= 1)
                s += __shfl_xor(s, off);
            if (l15 == 0) nrm[mf * 16 + g * 4 + ri][wn] = s;
        }
    __syncthreads();

    if (tid < BM2) {
        const int v = vbase + tid;
        float bn = nrm[tid][0];
        float sec = -1e30f;
        int best = 0;
        #pragma unroll
        for (int k = 1; k < NT; ++k) {
            float nv = nrm[tid][k];
            if (nv > bn)       { sec = bn; bn = nv; best = k; }
            else if (nv > sec) { sec = nv; }
        }
        // gap-err sigma ~3.6e-3 -> ~8 sigma (validated round 14, absmax 0.0156)
        const bool flag = (bn - sec) <= (3.0e-2f + 4e-4f * bn);
        besti[tid] = flag ? -1 : best;
        if (flag && v < NV) { int p = atomicAdd(wl, 1); wl[1 + p] = v; }
    }
    __syncthreads();

    #pragma unroll
    for (int mf = 0; mf < 4; ++mf)
        #pragma unroll
        for (int ri = 0; ri < 4; ++ri) {
            const int row = mf * 16 + g * 4 + ri;
            const int v   = vbase + row;
            const int bsel = (v < NV) ? besti[row] : -1;
            if (bsel == wn) {
                #pragma unroll
                for (int nf = 0; nf < 4; ++nf) {
                    const int d = nf * 16 + l15;
                    out[v * COUT + d] = fmaxf(acc[mf][nf][ri], 0.0f);
                }
            }
        }
}

// ---------- parallel fp64 refine: one BLOCK (4 waves) per vertex ----------
__global__ __launch_bounds__(256) void geo_refine_f64p(
    const float* __restrict__ signal,
    const float* __restrict__ bary_w,
    const int*   __restrict__ bary_idx,
    const float* __restrict__ kern,
    float*       __restrict__ out,
    const int*   __restrict__ wl,
    int nall)
{
    __shared__ __align__(16) float xs[NR][CIN][NT];
    __shared__ double part[4][NT][COUT];
    __shared__ double convl[NT][COUT];
    __shared__ double nks[NT];
    __shared__ int bestS;

    const int tid  = threadIdx.x;
    const int wave = tid >> 6;
    const int lane = tid & 63;
    const int count = wl ? wl[0] : nall;

    for (int w = blockIdx.x; w < count; w += gridDim.x) {
        const int v = wl ? wl[1 + w] : w;

        for (int ij = wave; ij < NR * NT; ij += 4) {
            const int i = ij >> 3, j = ij & 7;
            const int base = v * BARY + ij * 3;
            const float w0 = bary_w[base], w1 = bary_w[base+1], w2 = bary_w[base+2];
            const int   i0 = bary_idx[base], i1 = bary_idx[base+1], i2 = bary_idx[base+2];
            xs[i][lane][j] = w0 * signal[i0*CIN + lane]
                           + w1 * signal[i1*CIN + lane]
                           + w2 * signal[i2*CIN + lane];
        }
        __syncthreads();

        double acc[NT];
        #pragma unroll
        for (int k = 0; k < NT; ++k) acc[k] = 0.0;

        for (int r = wave * 80; r < wave * 80 + 80; ++r) {
            const int i = r >> 6, c = r & 63;
            const float4 xa = *reinterpret_cast<const float4*>(&xs[i][c][0]);
            const float4 xb = *reinterpret_cast<const float4*>(&xs[i][c][4]);
            const double x8[NT] = {(double)xa.x, (double)xa.y, (double)xa.z, (double)xa.w,
                                   (double)xb.x, (double)xb.y, (double)xb.z, (double)xb.w};
            #pragma unroll
            for (int mm = 0; mm < NT; ++mm) {
                const double kv = (double)kern[((i * NT + mm) * CIN + c) * COUT + lane];
                #pragma unroll
                for (int k = 0; k < NT; ++k)
                    acc[k] = fma(x8[(mm - k + NT) & (NT - 1)], kv, acc[k]);
            }
        }
        #pragma unroll
        for (int k = 0; k < NT; ++k) part[wave][k][lane] = acc[k];
        __syncthreads();

        for (int kd = tid; kd < NT * COUT; kd += 256) {
            const int k = kd >> 6, d = kd & 63;
            convl[k][d] = ((part[0][k][d] + part[1][k][d])
                         + (part[2][k][d] + part[3][k][d]));
        }
        __syncthreads();

        for (int k = wave; k < NT; k += 4) {
            double n = convl[k][lane] * convl[k][lane];
            #pragma unroll
            for (int off = 32; off >= 1; off >>= 1) n += __shfl_xor(n, off);
            if (lane == 0) nks[k] = n;
        }
        __syncthreads();

        if (tid == 0) {
            int best = 0; double bn = nks[0];
            #pragma unroll
            for (int k = 1; k < NT; ++k)
                if (nks[k] > bn) { bn = nks[k]; best = k; }
            bestS = best;
        }
        __syncthreads();

        if (tid < COUT) out[v * COUT + tid] = fmaxf((float)convl[bestS][tid], 0.0f);
        __syncthreads();
    }
}

extern "C" void kernel_launch(void* const* d_in, const int* in_sizes, int n_in,
                              void* d_out, int out_size, void* d_ws, size_t ws_size,
                              hipStream_t stream) {
    const float* signal   = (const float*)d_in[0];
    const float* bary_w   = (const float*)d_in[1];
    const int*   bary_idx = (const int*)d_in[2];
    const float* kern     = (const float*)d_in[3];
    float* out = (float*)d_out;

    if (ws_size >= (size_t)WS_NEED8) {
        int* wl = (int*)d_ws;
        _Float16* bkf   = (_Float16*)((char*)d_ws + WL_BYTES);
        _Float16* sig16 = (_Float16*)((char*)d_ws + WL_BYTES + 2u * BK_ELEMS);
        hipMemsetAsync(wl, 0, sizeof(int), stream);
        build_bk11<<<dim3(BK_ELEMS / 256), dim3(256), 0, stream>>>(kern, bkf);
        build_sig16<<<dim3(NV * CIN / 256), dim3(256), 0, stream>>>(signal, sig16);
        geo_mfma11<<<dim3(NBLK2), dim3(512), 0, stream>>>(
            bary_w, bary_idx, sig16, bkf, out, wl);
        geo_refine_f64p<<<dim3(1024), dim3(256), 0, stream>>>(
            signal, bary_w, bary_idx, kern, out, wl, 0);
    } else {
        geo_refine_f64p<<<dim3(1024), dim3(256), 0, stream>>>(
            signal, bary_w, bary_idx, kern, out, nullptr, NV);
    }
}

// Round 16
// 613.675 us; speedup vs baseline: 2.5177x; 1.8487x over previous
//
#include <hip/hip_runtime.h>

#define NV   50000
#define NR   5
#define NT   8
#define CIN  64
#define COUT 64
#define BARY (NR*NT*3)      // 120
#define BK_ELEMS (NR*CIN*NT*COUT)   // 163840 fp16 (320 KB) — L2-resident
#define BM2  64
#define NBLK2 ((NV + BM2 - 1) / BM2)   // 782
#define NCH  80             // chunks: (j 0..7) x (icc 0..9), K=32 each

#define WL_BYTES 262144
#define SIG16_BYTES (NV*CIN*2)                            // 6.4 MB
#define WS_NEED8 (WL_BYTES + 2u*BK_ELEMS + SIG16_BYTES)   // ~7.0 MB

typedef _Float16 f16x8 __attribute__((ext_vector_type(8)));
typedef _Float16 f16x4 __attribute__((ext_vector_type(4)));
typedef float    f32x4 __attribute__((ext_vector_type(4)));

// ---------- K0a: kernel -> fp16 ws with the LDS read-swizzle PRE-BAKED ----------
// Staging (BLOADR/BWRITE) copies bk linearly into Blds. The MFMA read uses
// granule u = gi ^ ((gi>>3)&7) (16B granules, involution), so we bake sigma here:
// bk[icc*16384 + u*8 + h]: gi = u^((u>>3)&7); col = gi>>2 (0..511); gq = gi&3;
// value = K[i=icc>>1, m=col>>6, c=(icc&1)*32 + gq*8 + h, d=col&63].
__global__ __launch_bounds__(256) void build_bk12(
    const float* __restrict__ kern, _Float16* __restrict__ bk)
{
    int e   = blockIdx.x * 256 + threadIdx.x;
    int h   = e & 7;
    int u   = (e >> 3) & 2047;
    int icc = e >> 14;
    int gi  = u ^ ((u >> 3) & 7);     // involution (bits 3-5 untouched)
    int col = gi >> 2;
    int gq  = gi & 3;
    int i   = icc >> 1;
    int c   = (icc & 1) * 32 + gq * 8 + h;
    int m   = col >> 6;
    int d   = col & 63;
    bk[e] = (_Float16)kern[((i * NT + m) * CIN + c) * COUT + d];
}

// ---------- K0b: signal -> fp16 ----------
__global__ __launch_bounds__(256) void build_sig16(
    const float* __restrict__ signal, _Float16* __restrict__ sig16)
{
    int e = blockIdx.x * 256 + threadIdx.x;
    sig16[e] = (_Float16)signal[e];
}

// ---------- main v12 = v7 + raw lgkm-only barriers + baked swizzle + setprio ----------
__global__ __launch_bounds__(512, 4) void geo_mfma12(
    const float* __restrict__ bary_w,
    const int*   __restrict__ bary_idx,
    const _Float16* __restrict__ sig16,
    const _Float16* __restrict__ bk,
    float* __restrict__ out,
    int*   __restrict__ wl)
{
    __shared__ __align__(16) _Float16 Blds[2][16384];   // 2 x 32 KB
    __shared__ __align__(16) _Float16 Axs[4][BM2][8];   // 4 KB (K=32, single-buf)
    __shared__ float nrm[BM2][NT];                      // 2 KB
    __shared__ int   besti[BM2];

    const int tid  = threadIdx.x;
    const int lane = tid & 63;
    const int wn   = tid >> 6;         // wave wn owns rotation k=wn
    const int g    = lane >> 4;
    const int l15  = lane & 15;
    const int vbase = blockIdx.x * BM2;

    // A-staging mapping: thread -> (vertex vt, ck-quad cq); 4 channels each
    const int vt = tid >> 3;
    const int cq = tid & 7;
    const int v_mine = vbase + vt;
    const bool v_ok = (v_mine < NV);

    f32x4 acc[4][4];
    {
        f32x4 z = {0.f, 0.f, 0.f, 0.f};
        #pragma unroll
        for (int mf = 0; mf < 4; ++mf)
            #pragma unroll
            for (int nf = 0; nf < 4; ++nf) acc[mf][nf] = z;
    }

    struct Gen { float w0, w1, w2; int i0, i1, i2; };
    auto LOADGEN = [&](int it2) -> Gen {
        Gen gg;
        const int itc = (it2 < NCH) ? it2 : (NCH - 1);
        const int j2   = itc / 10;
        const int icc2 = itc - j2 * 10;
        const int i2   = icc2 >> 1;
        if (v_ok) {
            const int base = v_mine * BARY + (i2 * NT + j2) * 3;
            gg.w0 = bary_w[base + 0];
            gg.w1 = bary_w[base + 1];
            gg.w2 = bary_w[base + 2];
            gg.i0 = bary_idx[base + 0];
            gg.i1 = bary_idx[base + 1];
            gg.i2 = bary_idx[base + 2];
        } else {
            gg.w0 = gg.w1 = gg.w2 = 0.f;
            gg.i0 = gg.i1 = gg.i2 = 0;
        }
        return gg;
    };

    f16x4 sA0, sA1, sA2, sB0, sB1, sB2;
    auto SIGLOAD = [&](const Gen& gg, int it2, f16x4& o0, f16x4& o1, f16x4& o2) {
        const int itc = (it2 < NCH) ? it2 : (NCH - 1);
        const int icc2 = itc - (itc / 10) * 10;
        const int coff = (icc2 & 1) * 32 + cq * 4;
        o0 = *(const f16x4*)(sig16 + gg.i0 * CIN + coff);
        o1 = *(const f16x4*)(sig16 + gg.i1 * CIN + coff);
        o2 = *(const f16x4*)(sig16 + gg.i2 * CIN + coff);
    };

    // B chunk reg-staging (linear copy; permutation pre-baked in ws)
    f16x8 breg0, breg1, breg2, breg3;
    auto BLOADR = [&](int icc2) {
        const _Float16* src = bk + icc2 * 16384 + wn * 2048 + lane * 8;
        breg0 = *(const f16x8*)(src + 0 * 512);
        breg1 = *(const f16x8*)(src + 1 * 512);
        breg2 = *(const f16x8*)(src + 2 * 512);
        breg3 = *(const f16x8*)(src + 3 * 512);
    };
    auto BWRITE = [&](int b) {
        _Float16* dst = &Blds[b][wn * 2048 + lane * 8];
        *(f16x8*)(dst + 0 * 512) = breg0;
        *(f16x8*)(dst + 1 * 512) = breg1;
        *(f16x8*)(dst + 2 * 512) = breg2;
        *(f16x8*)(dst + 3 * 512) = breg3;
    };

    // ---- prologue ----
    Gen g0 = LOADGEN(0);
    Gen g1 = LOADGEN(1);
    SIGLOAD(g0, 0, sA0, sA1, sA2);
    BLOADR(0);
    BWRITE(0);
    asm volatile("s_waitcnt lgkmcnt(0)" ::: "memory");
    __builtin_amdgcn_s_barrier();
    asm volatile("" ::: "memory");

    int cur = 0;
    #pragma unroll 1
    for (int it = 0; it < NCH; ++it) {
        const int j   = it / 10;
        const int m   = (j + wn) & 7;

        // ---- phase1: x(it) from regs -> Axs; issue next sig/bary ----
        {
            f16x4 hv;
            #pragma unroll
            for (int e = 0; e < 4; ++e) {
                float xf = g0.w0 * (float)sA0[e]
                         + g0.w1 * (float)sA1[e]
                         + g0.w2 * (float)sA2[e];
                hv[e] = (_Float16)xf;
            }
            *(f16x4*)&Axs[cq >> 1][vt][(cq & 1) * 4] = hv;
        }
        SIGLOAD(g1, it + 1, sB0, sB1, sB2);
        Gen g2 = LOADGEN(it + 2);
        // bar1: drain ONLY lgkm (the Axs ds_write); globals stay in flight
        asm volatile("s_waitcnt lgkmcnt(0)" ::: "memory");
        __builtin_amdgcn_s_barrier();
        asm volatile("" ::: "memory");

        // ---- phase2: issue B(it+1) loads early; MFMA from LDS; write B ----
        const int iccn = (it + 1 < NCH) ? ((it + 1) - ((it + 1) / 10) * 10) : 0;
        if (it + 1 < NCH) BLOADR(iccn);

        f16x8 afrag[4];
        #pragma unroll
        for (int mf = 0; mf < 4; ++mf)
            afrag[mf] = *(const f16x8*)&Axs[g][mf * 16 + l15][0];

        __builtin_amdgcn_s_setprio(1);
        #pragma unroll
        for (int nf = 0; nf < 4; ++nf) {
            const int col = m * 64 + nf * 16 + l15;
            const int gi  = col * 4 + g;
            const int u   = gi ^ ((gi >> 3) & 7);   // matches baked sigma
            const f16x8 bfrag = *(const f16x8*)&Blds[cur][u * 8];
            #pragma unroll
            for (int mf = 0; mf < 4; ++mf)
                acc[mf][nf] = __builtin_amdgcn_mfma_f32_16x16x32_f16(
                    afrag[mf], bfrag, acc[mf][nf], 0, 0, 0);
        }
        __builtin_amdgcn_s_setprio(0);

        if (it + 1 < NCH) BWRITE(cur ^ 1);   // compiler fences breg vmcnt here
        // bar2: drain ONLY lgkm (B ds_writes + all Blds/Axs ds_reads)
        asm volatile("s_waitcnt lgkmcnt(0)" ::: "memory");
        __builtin_amdgcn_s_barrier();
        asm volatile("" ::: "memory");

        // rotate pipeline (VALU copies; v7-proven inventory, VGPR 64)
        g0 = g1; g1 = g2;
        sA0 = sB0; sA1 = sB1; sA2 = sB2;
        cur ^= 1;
    }

    // ---- epilogue: wave wn owns rotation wn; norms per row ----
    #pragma unroll
    for (int mf = 0; mf < 4; ++mf)
        #pragma unroll
        for (int ri = 0; ri < 4; ++ri) {
            float s = 0.f;
            #pragma unroll
            for (int nf = 0; nf < 4; ++nf) {
                float vv = acc[mf][nf][ri];
                s = fmaf(vv, vv, s);
            }
            #pragma unroll
            for (int off = 1; off < 16; off <<= 1)
                s += __shfl_xor(s, off);
            if (l15 == 0) nrm[mf * 16 + g * 4 + ri][wn] = s;
        }
    __syncthreads();

    if (tid < BM2) {
        const int v = vbase + tid;
        float bn = nrm[tid][0];
        float sec = -1e30f;
        int best = 0;
        #pragma unroll
        for (int k = 1; k < NT; ++k) {
            float nv = nrm[tid][k];
            if (nv > bn)       { sec = bn; bn = nv; best = k; }
            else if (nv > sec) { sec = nv; }
        }
        // gap-err sigma ~3.6e-3 -> ~8 sigma (validated round 14)
        const bool flag = (bn - sec) <= (3.0e-2f + 4e-4f * bn);
        besti[tid] = flag ? -1 : best;
        if (flag && v < NV) { int p = atomicAdd(wl, 1); wl[1 + p] = v; }
    }
    __syncthreads();

    #pragma unroll
    for (int mf = 0; mf < 4; ++mf)
        #pragma unroll
        for (int ri = 0; ri < 4; ++ri) {
            const int row = mf * 16 + g * 4 + ri;
            const int v   = vbase + row;
            const int bsel = (v < NV) ? besti[row] : -1;
            if (bsel == wn) {
                #pragma unroll
                for (int nf = 0; nf < 4; ++nf) {
                    const int d = nf * 16 + l15;
                    out[v * COUT + d] = fmaxf(acc[mf][nf][ri], 0.0f);
                }
            }
        }
}

// ---------- parallel fp64 refine: one BLOCK (4 waves) per vertex ----------
__global__ __launch_bounds__(256) void geo_refine_f64p(
    const float* __restrict__ signal,
    const float* __restrict__ bary_w,
    const int*   __restrict__ bary_idx,
    const float* __restrict__ kern,
    float*       __restrict__ out,
    const int*   __restrict__ wl,
    int nall)
{
    __shared__ __align__(16) float xs[NR][CIN][NT];
    __shared__ double part[4][NT][COUT];
    __shared__ double convl[NT][COUT];
    __shared__ double nks[NT];
    __shared__ int bestS;

    const int tid  = threadIdx.x;
    const int wave = tid >> 6;
    const int lane = tid & 63;
    const int count = wl ? wl[0] : nall;

    for (int w = blockIdx.x; w < count; w += gridDim.x) {
        const int v = wl ? wl[1 + w] : w;

        for (int ij = wave; ij < NR * NT; ij += 4) {
            const int i = ij >> 3, j = ij & 7;
            const int base = v * BARY + ij * 3;
            const float w0 = bary_w[base], w1 = bary_w[base+1], w2 = bary_w[base+2];
            const int   i0 = bary_idx[base], i1 = bary_idx[base+1], i2 = bary_idx[base+2];
            xs[i][lane][j] = w0 * signal[i0*CIN + lane]
                           + w1 * signal[i1*CIN + lane]
                           + w2 * signal[i2*CIN + lane];
        }
        __syncthreads();

        double acc[NT];
        #pragma unroll
        for (int k = 0; k < NT; ++k) acc[k] = 0.0;

        for (int r = wave * 80; r < wave * 80 + 80; ++r) {
            const int i = r >> 6, c = r & 63;
            const float4 xa = *reinterpret_cast<const float4*>(&xs[i][c][0]);
            const float4 xb = *reinterpret_cast<const float4*>(&xs[i][c][4]);
            const double x8[NT] = {(double)xa.x, (double)xa.y, (double)xa.z, (double)xa.w,
                                   (double)xb.x, (double)xb.y, (double)xb.z, (double)xb.w};
            #pragma unroll
            for (int mm = 0; mm < NT; ++mm) {
                const double kv = (double)kern[((i * NT + mm) * CIN + c) * COUT + lane];
                #pragma unroll
                for (int k = 0; k < NT; ++k)
                    acc[k] = fma(x8[(mm - k + NT) & (NT - 1)], kv, acc[k]);
            }
        }
        #pragma unroll
        for (int k = 0; k < NT; ++k) part[wave][k][lane] = acc[k];
        __syncthreads();

        for (int kd = tid; kd < NT * COUT; kd += 256) {
            const int k = kd >> 6, d = kd & 63;
            convl[k][d] = ((part[0][k][d] + part[1][k][d])
                         + (part[2][k][d] + part[3][k][d]));
        }
        __syncthreads();

        for (int k = wave; k < NT; k += 4) {
            double n = convl[k][lane] * convl[k][lane];
            #pragma unroll
            for (int off = 32; off >= 1; off >>= 1) n += __shfl_xor(n, off);
            if (lane == 0) nks[k] = n;
        }
        __syncthreads();

        if (tid == 0) {
            int best = 0; double bn = nks[0];
            #pragma unroll
            for (int k = 1; k < NT; ++k)
                if (nks[k] > bn) { bn = nks[k]; best = k; }
            bestS = best;
        }
        __syncthreads();

        if (tid < COUT) out[v * COUT + tid] = fmaxf((float)convl[bestS][tid], 0.0f);
        __syncthreads();
    }
}

extern "C" void kernel_launch(void* const* d_in, const int* in_sizes, int n_in,
                              void* d_out, int out_size, void* d_ws, size_t ws_size,
                              hipStream_t stream) {
    const float* signal   = (const float*)d_in[0];
    const float* bary_w   = (const float*)d_in[1];
    const int*   bary_idx = (const int*)d_in[2];
    const float* kern     = (const float*)d_in[3];
    float* out = (float*)d_out;

    if (ws_size >= (size_t)WS_NEED8) {
        int* wl = (int*)d_ws;
        _Float16* bk    = (_Float16*)((char*)d_ws + WL_BYTES);
        _Float16* sig16 = (_Float16*)((char*)d_ws + WL_BYTES + 2u * BK_ELEMS);
        hipMemsetAsync(wl, 0, sizeof(int), stream);
        build_bk12<<<dim3(BK_ELEMS / 256), dim3(256), 0, stream>>>(kern, bk);
        build_sig16<<<dim3(NV * CIN / 256), dim3(256), 0, stream>>>(signal, sig16);
        geo_mfma12<<<dim3(NBLK2), dim3(512), 0, stream>>>(
            bary_w, bary_idx, sig16, bk, out, wl);
        geo_refine_f64p<<<dim3(1024), dim3(256), 0, stream>>>(
            signal, bary_w, bary_idx, kern, out, wl, 0);
    } else {
        geo_refine_f64p<<<dim3(1024), dim3(256), 0, stream>>>(
            signal, bary_w, bary_idx, kern, out, nullptr, NV);
    }
}